// Round 10
// baseline (186.075 us; speedup 1.0000x reference)
//
#include <hip/hip_runtime.h>
#include <hip/hip_bf16.h>

using u16 = unsigned short;
typedef __bf16 bf16x8 __attribute__((ext_vector_type(8)));
typedef float f32x4 __attribute__((ext_vector_type(4)));

#define N_B   16
#define L_S   512
#define D_F   256
#define T_MEL 4096
#define M_TOT (N_B * L_S)
#define OUT_ELEMS ((size_t)N_B * T_MEL * D_F)   // 16777216 fp32

__device__ __forceinline__ float bf2f(u16 v) {
  return __uint_as_float(((unsigned int)v) << 16);
}
__device__ __forceinline__ u16 f2bf(float f) {
  __hip_bfloat16 h = __float2bfloat16(f);
  return *(u16*)&h;
}

// ---------------------------------------------------------------------------
// Cast fp32 x -> bf16 scratch (lossless for bf16-grid values).
// ---------------------------------------------------------------------------
__global__ __launch_bounds__(256)
void cast_x_kernel(const float* __restrict__ x, u16* __restrict__ xbf) {
  int i = (blockIdx.x * 256 + threadIdx.x) * 4;     // 2,097,152 total elems
  float4 v = *(const float4*)(x + i);
  ushort4 r;
  r.x = f2bf(v.x); r.y = f2bf(v.y); r.z = f2bf(v.z); r.w = f2bf(v.w);
  *(ushort4*)(xbf + i) = r;
}

// ---------------------------------------------------------------------------
// Pack fp32 conv weights [F=256][D=256][K=3] -> bf16 Wp[s][f][ki]
// (s=0..23: kk=s*32+ki -> tap=s>>3, d=(s&7)*32+ki)
// ---------------------------------------------------------------------------
__global__ __launch_bounds__(256)
void pack_w_kernel(const float* __restrict__ w1, const float* __restrict__ w2,
                   u16* __restrict__ wp1, u16* __restrict__ wp2) {
  int o = blockIdx.x * 256 + threadIdx.x;
  if (o >= 24 * 256 * 32) return;
  int s   = o >> 13;
  int rem = o & 8191;
  int f   = rem >> 5;
  int ki  = rem & 31;
  int d   = ((s & 7) << 5) + ki;
  int tap = s >> 3;
  int src = f * 768 + d * 3 + tap;
  wp1[o] = f2bf(w1[src]);
  wp2[o] = f2bf(w2[src]);
}

// ---------------------------------------------------------------------------
// Fused conv1d(K=3) as im2col GEMM (M=8192,K=768,N=256) + bias + LN + ReLU.
// Inputs (x-tile, H, Wp) in bf16; LN params fp32; fp32 accumulate.
// STAGE 1: writes H (bf16 scratch). STAGE 2: fuses linear head -> dpo (fp32).
// ---------------------------------------------------------------------------
template<int STAGE>
__global__ __launch_bounds__(256)
void conv_ln_kernel(const u16* __restrict__ Xin, const u16* __restrict__ Wp,
                    const float* __restrict__ cb,  const float* __restrict__ lgm,
                    const float* __restrict__ lbt, const float* __restrict__ lw,
                    const float* __restrict__ lb,  u16* __restrict__ Hout,
                    float* __restrict__ dpo)
{
  __shared__ __align__(16) u16 As[32 * 40];
  __shared__ __align__(16) u16 Bs[256 * 40];
  __shared__ float sBias[256], sG[256], sB[256], sLw[256];
  __shared__ float redS[2][32], redQ[2][32];

  const int t = threadIdx.x;
  sBias[t] = cb[t];
  sG[t]    = lgm[t];
  sB[t]    = lbt[t];
  if (STAGE == 2) sLw[t] = lw[t];

  const int m0   = blockIdx.x * 32;
  const int n    = m0 >> 9;
  const int l0   = m0 & 511;
  const int wave = t >> 6, lane = t & 63;
  const int wr   = (wave & 1) * 16;
  const int wc   = (wave >> 1) * 128;
  const int p    = lane & 15, q = lane >> 4;

  f32x4 acc[8];
  #pragma unroll
  for (int i = 0; i < 8; i++) acc[i] = (f32x4){0.f, 0.f, 0.f, 0.f};

  const int ar = t >> 3, ak = (t & 7) * 4;
  const int bc = (t & 3) * 8, bf0 = t >> 2;

  uint2 pa;
  uint4 pb[4];
  auto LA = [&](int s) {
    const int tap = s >> 3, dbase = (s & 7) * 32;
    const int lsrc = l0 + ar + tap - 1;
    if (lsrc >= 0 && lsrc < L_S)
      pa = *(const uint2*)(Xin + ((size_t)((n << 9) + lsrc) << 8) + dbase + ak);
    else { pa.x = 0u; pa.y = 0u; }
  };
  auto LB = [&](int s) {
    const u16* src = Wp + ((size_t)s << 13) + bc;
    #pragma unroll
    for (int i = 0; i < 4; i++)
      pb[i] = *(const uint4*)(src + ((bf0 + (i << 6)) << 5));
  };
  LA(0); LB(0);

  for (int s = 0; s < 24; s++) {
    __syncthreads();
    *(uint2*)(As + ar * 40 + ak) = pa;
    #pragma unroll
    for (int i = 0; i < 4; i++)
      *(uint4*)(Bs + (bf0 + (i << 6)) * 40 + bc) = pb[i];
    if (s < 23) { LA(s + 1); LB(s + 1); }
    __syncthreads();
    bf16x8 af = *(const bf16x8*)(As + (wr + p) * 40 + q * 8);
    #pragma unroll
    for (int ct = 0; ct < 8; ct++) {
      bf16x8 bfr = *(const bf16x8*)(Bs + (wc + ct * 16 + p) * 40 + q * 8);
      acc[ct] = __builtin_amdgcn_mfma_f32_16x16x32_bf16(af, bfr, acc[ct], 0, 0, 0);
    }
  }

  // epilogue: bias + LN stats (row = wr+q*4+j, col = wc+ct*16+p)
  float s0[4] = {0,0,0,0}, s1[4] = {0,0,0,0};
  #pragma unroll
  for (int ct = 0; ct < 8; ct++) {
    float bias = sBias[wc + ct * 16 + p];
    #pragma unroll
    for (int j = 0; j < 4; j++) {
      float v = acc[ct][j] + bias;
      acc[ct][j] = v;
      s0[j] += v;
      s1[j] += v * v;
    }
  }
  #pragma unroll
  for (int m = 1; m <= 8; m <<= 1) {
    #pragma unroll
    for (int j = 0; j < 4; j++) {
      s0[j] += __shfl_xor(s0[j], m);
      s1[j] += __shfl_xor(s1[j], m);
    }
  }
  const int half = wave >> 1;
  if (p == 0) {
    #pragma unroll
    for (int j = 0; j < 4; j++) {
      redS[half][wr + q * 4 + j] = s0[j];
      redQ[half][wr + q * 4 + j] = s1[j];
    }
  }
  __syncthreads();
  float mean[4], rstd[4];
  #pragma unroll
  for (int j = 0; j < 4; j++) {
    int r = wr + q * 4 + j;
    float S = redS[0][r] + redS[1][r];
    float Q = redQ[0][r] + redQ[1][r];
    float mu  = S * (1.0f / 256.0f);
    float var = Q * (1.0f / 256.0f) - mu * mu;
    mean[j] = mu;
    rstd[j] = rsqrtf(var + 1e-5f);
  }

  if (STAGE == 1) {
    #pragma unroll
    for (int ct = 0; ct < 8; ct++) {
      int c = wc + ct * 16 + p;
      float gg = sG[c], bb = sB[c];
      #pragma unroll
      for (int j = 0; j < 4; j++) {
        float v = (acc[ct][j] - mean[j]) * rstd[j] * gg + bb;
        v = fmaxf(v, 0.0f);
        Hout[(size_t)(m0 + wr + q * 4 + j) * 256 + c] = f2bf(v);
      }
    }
  } else {
    float ls[4] = {0,0,0,0};
    #pragma unroll
    for (int ct = 0; ct < 8; ct++) {
      int c = wc + ct * 16 + p;
      float gg = sG[c], bb = sB[c], ww = sLw[c];
      #pragma unroll
      for (int j = 0; j < 4; j++) {
        float v = (acc[ct][j] - mean[j]) * rstd[j] * gg + bb;
        v = fmaxf(v, 0.0f);
        ls[j] += v * ww;
      }
    }
    #pragma unroll
    for (int m = 1; m <= 8; m <<= 1) {
      #pragma unroll
      for (int j = 0; j < 4; j++) ls[j] += __shfl_xor(ls[j], m);
    }
    __syncthreads();
    if (p == 0) {
      #pragma unroll
      for (int j = 0; j < 4; j++) redS[half][wr + q * 4 + j] = ls[j];
    }
    __syncthreads();
    if (half == 0 && p == 0) {
      float lbf = lb[0];
      #pragma unroll
      for (int j = 0; j < 4; j++) {
        int r = wr + q * 4 + j;
        float dv = fmaxf(redS[0][r] + redS[1][r] + lbf, 0.0f);
        dpo[m0 + r] = dv;                      // fp32 output
      }
    }
  }
}

// ---------------------------------------------------------------------------
// Length-regulate, all fp32:
//   idx = searchsorted(cumsum(dur), t, 'right'); out = valid ? x[n,idx,:] : 0
// Block = (n, 32 t's), grid 2048. Row = 256 fp32 = 64 float4 units.
// Bit-exact fp32 row copy; zeros where invalid.
// ---------------------------------------------------------------------------
__global__ __launch_bounds__(256)
void length_regulate_f32(const float* __restrict__ X, const int* __restrict__ tgt,
                         float* __restrict__ out) {
  __shared__ int c[L_S];
  __shared__ int sidx[32];
  const int t  = threadIdx.x;               // 0..255
  const int n  = blockIdx.x >> 7;           // 128 chunks per n
  const int t0 = (blockIdx.x & 127) * 32;

  c[t]       = tgt[n * L_S + t];
  c[t + 256] = tgt[n * L_S + t + 256];
  __syncthreads();

  if (t < 32) {
    const int tt = t0 + t;
    int run = 0;
    int idx = -1;
    for (int l = 0; l < L_S; l++) {
      run += c[l];                          // cum[l] inclusive
      if (idx < 0 && tt < run) idx = l;     // first l with cum[l] > tt
    }
    sidx[t] = idx;                          // -1 <=> tt >= total -> zeros
  }
  __syncthreads();

  // 32 rows x 64 float4 units = 2048 units; 256 thr x 8 iters
  #pragma unroll
  for (int i = 0; i < 8; i++) {
    int u   = t + i * 256;
    int dg  = u & 63;                       // float4 unit within row
    int tr  = u >> 6;                       // 0..31
    int idx = sidx[tr];
    float4 v = make_float4(0.f, 0.f, 0.f, 0.f);
    if (idx >= 0)
      v = *(const float4*)(X + (((size_t)(n * L_S + idx)) << 8) + dg * 4);
    *(float4*)(out + (((size_t)(n * T_MEL + t0 + tr)) << 8) + dg * 4) = v;
  }
}

// ---------------------------------------------------------------------------
extern "C" void kernel_launch(void* const* d_in, const int* in_sizes, int n_in,
                              void* d_out, int out_size, void* d_ws, size_t ws_size,
                              hipStream_t stream) {
  (void)d_ws; (void)ws_size; (void)in_sizes; (void)n_in; (void)out_size;

  const float* x   = (const float*)d_in[0];
  const float* w1  = (const float*)d_in[1];
  const float* b1  = (const float*)d_in[2];
  const float* g1  = (const float*)d_in[3];
  const float* be1 = (const float*)d_in[4];
  const float* w2  = (const float*)d_in[5];
  const float* b2  = (const float*)d_in[6];
  const float* g2  = (const float*)d_in[7];
  const float* be2 = (const float*)d_in[8];
  const float* lw  = (const float*)d_in[9];
  const float* lb  = (const float*)d_in[10];
  const int*   tgt = (const int*)d_in[11];

  float* out = (float*)d_out;                  // fp32 output buffer (67.1 MB)
  float* dpo = out + OUT_ELEMS;                // output 1 (fp32, 8192 elems)

  // bf16 scratch inside the fp32 output-0 region (first 67 MB), fully
  // overwritten by the final LR kernel:
  u16* xbf = (u16*)d_out;                      // 2,097,152 bf16 = 4 MB
  u16* h1  = xbf + 2097152;                    // 4 MB
  u16* wp1 = h1 + 2097152;                     // 384 KB
  u16* wp2 = wp1 + 196608;                     // 384 KB  (total < 9 MB)

  cast_x_kernel<<<2048, 256, 0, stream>>>(x, xbf);
  pack_w_kernel<<<768, 256, 0, stream>>>(w1, w2, wp1, wp2);
  conv_ln_kernel<1><<<M_TOT / 32, 256, 0, stream>>>(
      xbf, wp1, b1, g1, be1, nullptr, nullptr, h1, nullptr);
  conv_ln_kernel<2><<<M_TOT / 32, 256, 0, stream>>>(
      h1, wp2, b2, g2, be2, lw, lb, nullptr, dpo);

  length_regulate_f32<<<N_B * (T_MEL / 32), 256, 0, stream>>>(x, tgt, out);
}

// Round 12
// 178.471 us; speedup vs baseline: 1.0426x; 1.0426x over previous
//
#include <hip/hip_runtime.h>
#include <hip/hip_bf16.h>

using u16 = unsigned short;
typedef __bf16 bf16x8 __attribute__((ext_vector_type(8)));
typedef float f32x4 __attribute__((ext_vector_type(4)));

#define N_B   16
#define L_S   512
#define D_F   256
#define T_MEL 4096
#define M_TOT (N_B * L_S)
#define OUT_ELEMS ((size_t)N_B * T_MEL * D_F)   // fp32 elems

__device__ __forceinline__ float bf2f(u16 v) {
  return __uint_as_float(((unsigned int)v) << 16);
}
__device__ __forceinline__ u16 f2bf(float f) {
  __hip_bfloat16 h = __float2bfloat16(f);
  return *(u16*)&h;
}

// ---------------------------------------------------------------------------
// PREP (fused): blocks 0..2047 cast x fp32->bf16; blocks 2048..2815 pack
// conv weights [F=256][D=256][K=3] fp32 -> bf16 Wp[s][f][ki]
// (kk = s*32+ki -> tap = s>>3, d = (s&7)*32+ki).
// Identical math to round-10's cast_x_kernel + pack_w_kernel (proven).
// ---------------------------------------------------------------------------
__global__ __launch_bounds__(256)
void prep_kernel(const float* __restrict__ x,  u16* __restrict__ xbf,
                 const float* __restrict__ w1, const float* __restrict__ w2,
                 u16* __restrict__ wp1, u16* __restrict__ wp2) {
  const int blk = blockIdx.x, t = threadIdx.x;
  if (blk < 2048) {
    int i = (blk * 256 + t) * 4;
    float4 v = *(const float4*)(x + i);
    ushort4 r;
    r.x = f2bf(v.x); r.y = f2bf(v.y); r.z = f2bf(v.z); r.w = f2bf(v.w);
    *(ushort4*)(xbf + i) = r;
  } else {
    int o = (blk - 2048) * 256 + t;          // 0..196607
    int s   = o >> 13;
    int rem = o & 8191;
    int f   = rem >> 5;
    int ki  = rem & 31;
    int d   = ((s & 7) << 5) + ki;
    int tap = s >> 3;
    int src = f * 768 + d * 3 + tap;
    wp1[o] = f2bf(w1[src]);
    wp2[o] = f2bf(w2[src]);
  }
}

// ---------------------------------------------------------------------------
// Fused conv1d(K=3) im2col GEMM + bias + LN + ReLU — ROUND-10 VERSION,
// VERBATIM (proven: dpo absmax 0.0034). 256 blocks x 256 thr, 32-row tiles.
// ---------------------------------------------------------------------------
template<int STAGE>
__global__ __launch_bounds__(256)
void conv_ln_kernel(const u16* __restrict__ Xin, const u16* __restrict__ Wp,
                    const float* __restrict__ cb,  const float* __restrict__ lgm,
                    const float* __restrict__ lbt, const float* __restrict__ lw,
                    const float* __restrict__ lb,  u16* __restrict__ Hout,
                    float* __restrict__ dpo)
{
  __shared__ __align__(16) u16 As[32 * 40];
  __shared__ __align__(16) u16 Bs[256 * 40];
  __shared__ float sBias[256], sG[256], sB[256], sLw[256];
  __shared__ float redS[2][32], redQ[2][32];

  const int t = threadIdx.x;
  sBias[t] = cb[t];
  sG[t]    = lgm[t];
  sB[t]    = lbt[t];
  if (STAGE == 2) sLw[t] = lw[t];

  const int m0   = blockIdx.x * 32;
  const int n    = m0 >> 9;
  const int l0   = m0 & 511;
  const int wave = t >> 6, lane = t & 63;
  const int wr   = (wave & 1) * 16;
  const int wc   = (wave >> 1) * 128;
  const int p    = lane & 15, q = lane >> 4;

  f32x4 acc[8];
  #pragma unroll
  for (int i = 0; i < 8; i++) acc[i] = (f32x4){0.f, 0.f, 0.f, 0.f};

  const int ar = t >> 3, ak = (t & 7) * 4;
  const int bc = (t & 3) * 8, bf0 = t >> 2;

  uint2 pa;
  uint4 pb[4];
  auto LA = [&](int s) {
    const int tap = s >> 3, dbase = (s & 7) * 32;
    const int lsrc = l0 + ar + tap - 1;
    if (lsrc >= 0 && lsrc < L_S)
      pa = *(const uint2*)(Xin + ((size_t)((n << 9) + lsrc) << 8) + dbase + ak);
    else { pa.x = 0u; pa.y = 0u; }
  };
  auto LB = [&](int s) {
    const u16* src = Wp + ((size_t)s << 13) + bc;
    #pragma unroll
    for (int i = 0; i < 4; i++)
      pb[i] = *(const uint4*)(src + ((bf0 + (i << 6)) << 5));
  };
  LA(0); LB(0);

  for (int s = 0; s < 24; s++) {
    __syncthreads();
    *(uint2*)(As + ar * 40 + ak) = pa;
    #pragma unroll
    for (int i = 0; i < 4; i++)
      *(uint4*)(Bs + (bf0 + (i << 6)) * 40 + bc) = pb[i];
    if (s < 23) { LA(s + 1); LB(s + 1); }
    __syncthreads();
    bf16x8 af = *(const bf16x8*)(As + (wr + p) * 40 + q * 8);
    #pragma unroll
    for (int ct = 0; ct < 8; ct++) {
      bf16x8 bfr = *(const bf16x8*)(Bs + (wc + ct * 16 + p) * 40 + q * 8);
      acc[ct] = __builtin_amdgcn_mfma_f32_16x16x32_bf16(af, bfr, acc[ct], 0, 0, 0);
    }
  }

  float s0[4] = {0,0,0,0}, s1[4] = {0,0,0,0};
  #pragma unroll
  for (int ct = 0; ct < 8; ct++) {
    float bias = sBias[wc + ct * 16 + p];
    #pragma unroll
    for (int j = 0; j < 4; j++) {
      float v = acc[ct][j] + bias;
      acc[ct][j] = v;
      s0[j] += v;
      s1[j] += v * v;
    }
  }
  #pragma unroll
  for (int m = 1; m <= 8; m <<= 1) {
    #pragma unroll
    for (int j = 0; j < 4; j++) {
      s0[j] += __shfl_xor(s0[j], m);
      s1[j] += __shfl_xor(s1[j], m);
    }
  }
  const int half = wave >> 1;
  if (p == 0) {
    #pragma unroll
    for (int j = 0; j < 4; j++) {
      redS[half][wr + q * 4 + j] = s0[j];
      redQ[half][wr + q * 4 + j] = s1[j];
    }
  }
  __syncthreads();
  float mean[4], rstd[4];
  #pragma unroll
  for (int j = 0; j < 4; j++) {
    int r = wr + q * 4 + j;
    float S = redS[0][r] + redS[1][r];
    float Q = redQ[0][r] + redQ[1][r];
    float mu  = S * (1.0f / 256.0f);
    float var = Q * (1.0f / 256.0f) - mu * mu;
    mean[j] = mu;
    rstd[j] = rsqrtf(var + 1e-5f);
  }

  if (STAGE == 1) {
    #pragma unroll
    for (int ct = 0; ct < 8; ct++) {
      int c = wc + ct * 16 + p;
      float gg = sG[c], bb = sB[c];
      #pragma unroll
      for (int j = 0; j < 4; j++) {
        float v = (acc[ct][j] - mean[j]) * rstd[j] * gg + bb;
        v = fmaxf(v, 0.0f);
        Hout[(size_t)(m0 + wr + q * 4 + j) * 256 + c] = f2bf(v);
      }
    }
  } else {
    float ls[4] = {0,0,0,0};
    #pragma unroll
    for (int ct = 0; ct < 8; ct++) {
      int c = wc + ct * 16 + p;
      float gg = sG[c], bb = sB[c], ww = sLw[c];
      #pragma unroll
      for (int j = 0; j < 4; j++) {
        float v = (acc[ct][j] - mean[j]) * rstd[j] * gg + bb;
        v = fmaxf(v, 0.0f);
        ls[j] += v * ww;
      }
    }
    #pragma unroll
    for (int m = 1; m <= 8; m <<= 1) {
      #pragma unroll
      for (int j = 0; j < 4; j++) ls[j] += __shfl_xor(ls[j], m);
    }
    __syncthreads();
    if (p == 0) {
      #pragma unroll
      for (int j = 0; j < 4; j++) redS[half][wr + q * 4 + j] = ls[j];
    }
    __syncthreads();
    if (half == 0 && p == 0) {
      float lbf = lb[0];
      #pragma unroll
      for (int j = 0; j < 4; j++) {
        int r = wr + q * 4 + j;
        float dv = fmaxf(redS[0][r] + redS[1][r] + lbf, 0.0f);
        dpo[m0 + r] = dv;
      }
    }
  }
}

// ---------------------------------------------------------------------------
// Length-regulate (fp32): parallel Hillis-Steele scan + binary search.
// Proven correct in round 11 (output 0 bit-exact).
// ---------------------------------------------------------------------------
#define TBLK 128
__global__ __launch_bounds__(256)
void lr_kernel(const float* __restrict__ X, const int* __restrict__ tgt,
               float* __restrict__ out) {
  __shared__ int c[L_S];
  __shared__ int sidx[TBLK];
  const int t  = threadIdx.x;               // 0..255
  const int n  = blockIdx.x >> 5;           // 32 chunks per n
  const int t0 = (blockIdx.x & 31) * TBLK;

  c[t]       = tgt[n * L_S + t];
  c[t + 256] = tgt[n * L_S + t + 256];
  __syncthreads();
  for (int off = 1; off < L_S; off <<= 1) {
    int v0 = (t >= off) ? c[t - off] : 0;
    int i1 = t + 256;
    int v1 = (i1 >= off) ? c[i1 - off] : 0;
    __syncthreads();
    c[t]  += v0;
    c[i1] += v1;
    __syncthreads();
  }
  const int total = c[L_S - 1];
  if (t < TBLK) {
    int tt = t0 + t;
    int lo = 0, hi = L_S;
    while (lo < hi) {                       // upper_bound: first c[i] > tt
      int mid = (lo + hi) >> 1;
      if (c[mid] <= tt) lo = mid + 1; else hi = mid;
    }
    sidx[t] = (tt < total) ? lo : -1;
  }
  __syncthreads();

  #pragma unroll
  for (int i = 0; i < 32; i++) {
    int u   = t + i * 256;                  // 128 rows x 64 float4
    int dg  = u & 63;
    int tr  = u >> 6;
    int idx = sidx[tr];
    float4 v = make_float4(0.f, 0.f, 0.f, 0.f);
    if (idx >= 0)
      v = *(const float4*)(X + (((size_t)(n * L_S + idx)) << 8) + dg * 4);
    *(float4*)(out + (((size_t)(n * T_MEL + t0 + tr)) << 8) + dg * 4) = v;
  }
}

// ---------------------------------------------------------------------------
extern "C" void kernel_launch(void* const* d_in, const int* in_sizes, int n_in,
                              void* d_out, int out_size, void* d_ws, size_t ws_size,
                              hipStream_t stream) {
  (void)d_ws; (void)ws_size; (void)in_sizes; (void)n_in; (void)out_size;

  const float* x   = (const float*)d_in[0];
  const float* w1  = (const float*)d_in[1];
  const float* b1  = (const float*)d_in[2];
  const float* g1  = (const float*)d_in[3];
  const float* be1 = (const float*)d_in[4];
  const float* w2  = (const float*)d_in[5];
  const float* b2  = (const float*)d_in[6];
  const float* g2  = (const float*)d_in[7];
  const float* be2 = (const float*)d_in[8];
  const float* lw  = (const float*)d_in[9];
  const float* lb  = (const float*)d_in[10];
  const int*   tgt = (const int*)d_in[11];

  float* out = (float*)d_out;
  float* dpo = out + OUT_ELEMS;

  // bf16 scratch inside the fp32 output-0 region; overwritten by final LR.
  u16* xbf = (u16*)d_out;
  u16* h1  = xbf + 2097152;
  u16* wp1 = h1 + 2097152;
  u16* wp2 = wp1 + 196608;

  prep_kernel<<<2816, 256, 0, stream>>>(x, xbf, w1, w2, wp1, wp2);
  conv_ln_kernel<1><<<M_TOT / 32, 256, 0, stream>>>(
      xbf, wp1, b1, g1, be1, nullptr, nullptr, h1, nullptr);
  conv_ln_kernel<2><<<M_TOT / 32, 256, 0, stream>>>(
      h1, wp2, b2, g2, be2, lw, lb, nullptr, dpo);
  lr_kernel<<<N_B * (T_MEL / TBLK), 256, 0, stream>>>(x, tgt, out);
}